// Round 6
// baseline (102.647 us; speedup 1.0000x reference)
//
#include <hip/hip_runtime.h>

#define N_PTS 131072
#define DIM   128
#define KC    512
#define NT    4                 // n-tiles (of 16 points) per wave
#define WAVES 4
#define BLOCK (WAVES * 64)
#define PTS_PER_WG (WAVES * NT * 16)   // 256
#define KTILES (KC / 16)               // 32
#define TILE_BYTES 8192                // hi 4KB + lo 4KB per k-tile (swizzled)
#define CHUNK 4                        // k-tiles staged per phase
#define CHUNK_BYTES (CHUNK * TILE_BYTES)   // 32 KB
#define NCHUNKS (KTILES / CHUNK)           // 8

typedef _Float16 half8 __attribute__((ext_vector_type(8)));
typedef float    f32x4 __attribute__((ext_vector_type(4)));

// ---------------- prep: centroids fp32 -> swizzled f16 hi/lo tiles + csq --------
// tile kt = [hi 4KB | lo 4KB]; row r (=k&15) at r*256; byte b(dim d)=2d stored
// at b ^ ((r&7)<<4)   (16B-granular XOR swizzle)
__global__ __launch_bounds__(128)
void prep_centroids(const float* __restrict__ c,
                    unsigned char* __restrict__ tiles,
                    float* __restrict__ csq) {
    const int k = blockIdx.x;
    const int d = threadIdx.x;
    float v = c[k * DIM + d];
    _Float16 hi = (_Float16)v;
    _Float16 lo = (_Float16)(v - (float)hi);

    const int kt = k >> 4, row = k & 15;
    const unsigned bsw = (unsigned)(2 * d) ^ (unsigned)((row & 7) << 4);
    unsigned char* tb = tiles + (size_t)kt * TILE_BYTES + row * 256 + bsw;
    *(_Float16*)(tb)        = hi;
    *(_Float16*)(tb + 4096) = lo;

    float s = v * v;
    #pragma unroll
    for (int off = 1; off < 64; off <<= 1) s += __shfl_xor(s, off);
    __shared__ float red[2];
    if ((d & 63) == 0) red[d >> 6] = s;
    __syncthreads();
    if (d == 0) csq[k] = red[0] + red[1];
}

// async global->LDS, 16B per lane (dest = wave-uniform base + lane*16 by HW)
__device__ __forceinline__ void stage16(const void* g, void* l) {
    __builtin_amdgcn_global_load_lds(
        (const __attribute__((address_space(1))) void*)g,
        (__attribute__((address_space(3))) void*)l, 16, 0, 0);
}

// stage one whole 8KB tile with this wave (8 x 1KB)
__device__ __forceinline__ void stage_tile(const unsigned char* src_tile,
                                           unsigned char* dst_tile, int lane) {
    #pragma unroll
    for (int j = 0; j < 8; ++j)
        stage16(src_tile + j * 1024 + lane * 16, dst_tile + j * 1024);
}

// ---------------- main: chunked LDS pipeline (4 tiles/phase), fused argmin ------
__global__ __launch_bounds__(BLOCK, 2)
void kmeans_mfma(const float* __restrict__ x,
                 const unsigned char* __restrict__ tiles,
                 const float* __restrict__ csq,
                 float* __restrict__ dist,
                 float* __restrict__ assign_out) {
    __shared__ alignas(16) unsigned char abuf[2 * CHUNK_BYTES];
    __shared__ alignas(16) float csq_lds[KC];

    const int tid  = threadIdx.x;
    const int wave = tid >> 6;
    const int lane = tid & 63;
    const int col  = lane & 15;       // n within tile / A row within k-tile
    const int g    = lane >> 4;       // lane group -> k-slot block / C row group
    const int n0   = blockIdx.x * PTS_PER_WG + wave * (NT * 16);

    // ---- stage chunk 0 (wave w stages tile w) ----
    stage_tile(tiles + (size_t)wave * TILE_BYTES,
               abuf + wave * TILE_BYTES, lane);

    // ---- csq -> LDS ----
    csq_lds[tid]       = csq[tid];
    csq_lds[tid + 256] = csq[tid + 256];

    // ---- B-frags: this wave's 64 points, hi/lo f16, resident in VGPRs ----
    half8 bhi[NT][4], blo[NT][4];
    float xsq[NT];
    #pragma unroll
    for (int t = 0; t < NT; ++t) {
        const float* xp = x + (size_t)(n0 + t * 16 + col) * DIM;
        float s = 0.f;
        #pragma unroll
        for (int sb = 0; sb < 4; ++sb) {
            const int dbase = sb * 32 + g * 8;
            float4 v0 = *(const float4*)(xp + dbase);
            float4 v1 = *(const float4*)(xp + dbase + 4);
            float vv[8] = {v0.x, v0.y, v0.z, v0.w, v1.x, v1.y, v1.z, v1.w};
            half8 h, l;
            #pragma unroll
            for (int j = 0; j < 8; ++j) {
                _Float16 hh = (_Float16)vv[j];
                h[j] = hh;
                l[j] = (_Float16)(vv[j] - (float)hh);
                s = fmaf(vv[j], vv[j], s);
            }
            bhi[t][sb] = h;
            blo[t][sb] = l;
        }
        s += __shfl_xor(s, 16);
        s += __shfl_xor(s, 32);
        xsq[t] = s;
    }

    float bestd[NT];
    int   bestk[NT];
    #pragma unroll
    for (int t = 0; t < NT; ++t) { bestd[t] = INFINITY; bestk[t] = 0; }

    __syncthreads();   // one-time full drain: chunk-0 stage + csq writes visible

    int cur = 0;
    for (int c = 0; c < NCHUNKS; ++c) {
        // ---- issue next chunk's stage FIRST (hides under 4 tiles of work) ----
        if (c + 1 < NCHUNKS) {
            stage_tile(tiles + (size_t)((c + 1) * CHUNK + wave) * TILE_BYTES,
                       abuf + (cur ^ 1) * CHUNK_BYTES + wave * TILE_BYTES, lane);
        }
        __builtin_amdgcn_sched_barrier(0);

        // ---- 4 tiles, barrier-free: ds_read -> MFMA -> store+argmin ----
        #pragma unroll
        for (int i = 0; i < CHUNK; ++i) {
            const int kt = c * CHUNK + i;
            const unsigned char* buf = abuf + cur * CHUNK_BYTES + i * TILE_BYTES;

            half8 Ah[4], Al[4];
            #pragma unroll
            for (int sb = 0; sb < 4; ++sb) {
                const unsigned b = (unsigned)((sb * 64 + g * 16) ^ ((col & 7) << 4));
                Ah[sb] = *(const half8*)(buf + col * 256 + b);
                Al[sb] = *(const half8*)(buf + 4096 + col * 256 + b);
            }
            f32x4 cs4 = *(const f32x4*)(&csq_lds[kt * 16 + g * 4]);

            f32x4 acc[NT];
            #pragma unroll
            for (int t = 0; t < NT; ++t) {
                f32x4 a_ = {0.f, 0.f, 0.f, 0.f};
                #pragma unroll
                for (int sb = 0; sb < 4; ++sb) {
                    a_ = __builtin_amdgcn_mfma_f32_16x16x32_f16(Ah[sb], bhi[t][sb], a_, 0, 0, 0);
                    a_ = __builtin_amdgcn_mfma_f32_16x16x32_f16(Ah[sb], blo[t][sb], a_, 0, 0, 0);
                    a_ = __builtin_amdgcn_mfma_f32_16x16x32_f16(Al[sb], bhi[t][sb], a_, 0, 0, 0);
                }
                acc[t] = a_;
            }

            #pragma unroll
            for (int r = 0; r < 4; ++r) {
                const int kr = kt * 16 + g * 4 + r;
                float* drow = dist + (size_t)kr * N_PTS + n0 + col;
                #pragma unroll
                for (int t = 0; t < NT; ++t) {
                    float dv = fmaf(-2.f, acc[t][r], xsq[t] + cs4[r]);
                    drow[t * 16] = dv;
                    if (dv < bestd[t]) { bestd[t] = dv; bestk[t] = kr; }
                }
            }
        }

        // ---- counted wait: 3 stage + 64 stores issued after the 1st stage op;
        //      vmcnt(63) guarantees all 8 stage loads retired, leaves ~63 ops
        //      (a full chunk of stores) in flight ----
        if (c + 1 < NCHUNKS) {
            asm volatile("s_waitcnt vmcnt(63)" ::: "memory");
            __builtin_amdgcn_sched_barrier(0);
            __builtin_amdgcn_s_barrier();
            cur ^= 1;
        }
    }

    // ---- cross-lane argmin over the 4 lane groups ----
    #pragma unroll
    for (int t = 0; t < NT; ++t) {
        float d = bestd[t];
        int   k = bestk[t];
        #pragma unroll
        for (int off = 16; off < 64; off <<= 1) {
            float od = __shfl_xor(d, off);
            int   ok = __shfl_xor(k, off);
            if (od < d || (od == d && ok < k)) { d = od; k = ok; }
        }
        if (g == 0) assign_out[n0 + t * 16 + col] = (float)k;
    }
}

extern "C" void kernel_launch(void* const* d_in, const int* in_sizes, int n_in,
                              void* d_out, int out_size, void* d_ws, size_t ws_size,
                              hipStream_t stream) {
    const float* x = (const float*)d_in[0];   // [N, D]
    const float* c = (const float*)d_in[1];   // [K, D]
    float* dist       = (float*)d_out;                 // [K, N]
    float* assign_out = dist + (size_t)KC * N_PTS;     // [N] as float

    // ws: swizzled tiles [32 * 8KB = 256KB] | csq f32[512]
    unsigned char* tiles = (unsigned char*)d_ws;
    float* csq = (float*)(tiles + (size_t)KTILES * TILE_BYTES);

    prep_centroids<<<KC, DIM, 0, stream>>>(c, tiles, csq);
    kmeans_mfma<<<N_PTS / PTS_PER_WG, BLOCK, 0, stream>>>(x, tiles, csq, dist, assign_out);
}

// Round 7
// 91.575 us; speedup vs baseline: 1.1209x; 1.1209x over previous
//
#include <hip/hip_runtime.h>

#define N_PTS 131072
#define DIM   128
#define KC    512
#define NT    4                 // n-tiles (of 16 points) per wave
#define WAVES 4
#define BLOCK (WAVES * 64)
#define PTS_PER_WG (WAVES * NT * 16)   // 256
#define KTILES (KC / 16)               // 32
#define TILE_BYTES 8192                // hi 4KB + lo 4KB per k-tile (swizzled)

typedef _Float16 half8 __attribute__((ext_vector_type(8)));
typedef float    f32x4 __attribute__((ext_vector_type(4)));

// ---------------- prep: centroids fp32 -> swizzled f16 hi/lo tiles + csq --------
// tile kt = [hi 4KB | lo 4KB]; row r (=k&15) at r*256; byte b(dim d)=2d stored
// at b ^ ((r&7)<<4)   (16B-granular XOR swizzle)
__global__ __launch_bounds__(128)
void prep_centroids(const float* __restrict__ c,
                    unsigned char* __restrict__ tiles,
                    float* __restrict__ csq) {
    const int k = blockIdx.x;
    const int d = threadIdx.x;
    float v = c[k * DIM + d];
    _Float16 hi = (_Float16)v;
    _Float16 lo = (_Float16)(v - (float)hi);

    const int kt = k >> 4, row = k & 15;
    const unsigned bsw = (unsigned)(2 * d) ^ (unsigned)((row & 7) << 4);
    unsigned char* tb = tiles + (size_t)kt * TILE_BYTES + row * 256 + bsw;
    *(_Float16*)(tb)        = hi;
    *(_Float16*)(tb + 4096) = lo;

    float s = v * v;
    #pragma unroll
    for (int off = 1; off < 64; off <<= 1) s += __shfl_xor(s, off);
    __shared__ float red[2];
    if ((d & 63) == 0) red[d >> 6] = s;
    __syncthreads();
    if (d == 0) csq[k] = red[0] + red[1];
}

// async global->LDS, 16B per lane (dest = wave-uniform base + lane*16 by HW)
__device__ __forceinline__ void stage16(const void* g, void* l) {
    __builtin_amdgcn_global_load_lds(
        (const __attribute__((address_space(1))) void*)g,
        (__attribute__((address_space(3))) void*)l, 16, 0, 0);
}

// ---------------- main: LDS-staged A (dbuf) + LDS-transposed store epilogue -----
__global__ __launch_bounds__(BLOCK, 2)
void kmeans_mfma(const float* __restrict__ x,
                 const unsigned char* __restrict__ tiles,
                 const float* __restrict__ csq,
                 float* __restrict__ dist,
                 float* __restrict__ assign_out) {
    __shared__ alignas(16) unsigned char abuf[2 * TILE_BYTES];
    __shared__ alignas(16) float csq_lds[KC];
    __shared__ alignas(16) float scratch[WAVES][16][64];   // per-wave transpose buf

    const int tid  = threadIdx.x;
    const int wave = tid >> 6;
    const int lane = tid & 63;
    const int col  = lane & 15;       // n within tile / A row within k-tile
    const int g    = lane >> 4;       // lane group -> k-slot block / C row group
    const int n0   = blockIdx.x * PTS_PER_WG + wave * (NT * 16);

    // ---- stage tile 0 (each wave copies its 2KB slice) ----
    {
        const unsigned char* src = tiles + (size_t)(wave * 2) * 1024 + lane * 16;
        unsigned char* dst = abuf + (wave * 2) * 1024;
        stage16(src, dst);
        stage16(src + 1024, dst + 1024);
    }

    // ---- csq -> LDS ----
    csq_lds[tid]       = csq[tid];
    csq_lds[tid + 256] = csq[tid + 256];

    // ---- B-frags: this wave's 64 points, hi/lo f16, resident in VGPRs ----
    half8 bhi[NT][4], blo[NT][4];
    float xsq[NT];
    #pragma unroll
    for (int t = 0; t < NT; ++t) {
        const float* xp = x + (size_t)(n0 + t * 16 + col) * DIM;
        float s = 0.f;
        #pragma unroll
        for (int sb = 0; sb < 4; ++sb) {
            const int dbase = sb * 32 + g * 8;
            float4 v0 = *(const float4*)(xp + dbase);
            float4 v1 = *(const float4*)(xp + dbase + 4);
            float vv[8] = {v0.x, v0.y, v0.z, v0.w, v1.x, v1.y, v1.z, v1.w};
            half8 h, l;
            #pragma unroll
            for (int j = 0; j < 8; ++j) {
                _Float16 hh = (_Float16)vv[j];
                h[j] = hh;
                l[j] = (_Float16)(vv[j] - (float)hh);
                s = fmaf(vv[j], vv[j], s);
            }
            bhi[t][sb] = h;
            blo[t][sb] = l;
        }
        s += __shfl_xor(s, 16);
        s += __shfl_xor(s, 32);
        xsq[t] = s;
    }

    float bestd[NT];
    int   bestk[NT];
    #pragma unroll
    for (int t = 0; t < NT; ++t) { bestd[t] = INFINITY; bestk[t] = 0; }

    __syncthreads();   // tile-0 stage + csq writes visible

    int cur = 0;
    for (int kt = 0; kt < KTILES; ++kt) {
        // ---- issue next tile's stage FIRST (hides under MFMA+epilogue) ----
        if (kt + 1 < KTILES) {
            const unsigned char* src = tiles + (size_t)(kt + 1) * TILE_BYTES
                                     + (wave * 2) * 1024 + lane * 16;
            unsigned char* dst = abuf + (cur ^ 1) * TILE_BYTES + (wave * 2) * 1024;
            stage16(src, dst);
            stage16(src + 1024, dst + 1024);
        }
        __builtin_amdgcn_sched_barrier(0);

        // ---- A-frags from LDS (swizzled read matches prep layout) ----
        const unsigned char* buf = abuf + cur * TILE_BYTES;
        half8 Ah[4], Al[4];
        #pragma unroll
        for (int sb = 0; sb < 4; ++sb) {
            const unsigned b = (unsigned)((sb * 64 + g * 16) ^ ((col & 7) << 4));
            Ah[sb] = *(const half8*)(buf + col * 256 + b);
            Al[sb] = *(const half8*)(buf + 4096 + col * 256 + b);
        }
        f32x4 cs4 = *(const f32x4*)(&csq_lds[kt * 16 + g * 4]);

        // ---- MFMA: 3-pass split-f16, NT independent chains ----
        f32x4 acc[NT];
        #pragma unroll
        for (int t = 0; t < NT; ++t) {
            f32x4 a_ = {0.f, 0.f, 0.f, 0.f};
            #pragma unroll
            for (int sb = 0; sb < 4; ++sb) {
                a_ = __builtin_amdgcn_mfma_f32_16x16x32_f16(Ah[sb], bhi[t][sb], a_, 0, 0, 0);
                a_ = __builtin_amdgcn_mfma_f32_16x16x32_f16(Ah[sb], blo[t][sb], a_, 0, 0, 0);
                a_ = __builtin_amdgcn_mfma_f32_16x16x32_f16(Al[sb], bhi[t][sb], a_, 0, 0, 0);
            }
            acc[t] = a_;
        }

        // ---- epilogue A: dv -> per-wave LDS scratch (swizzled) + argmin ----
        // logical (row = g*4+r, fi = t*16+col); sfi = fi ^ ((row>>2)<<4) ^ ((row&3)<<3)
        #pragma unroll
        for (int r = 0; r < 4; ++r) {
            const int row = g * 4 + r;
            #pragma unroll
            for (int t = 0; t < NT; ++t) {
                float dv = fmaf(-2.f, acc[t][r], xsq[t] + cs4[r]);
                const int sfi = (t * 16 + col) ^ (g << 4) ^ (r << 3);
                scratch[wave][row][sfi] = dv;
                const int kr = kt * 16 + row;
                if (dv < bestd[t]) { bestd[t] = dv; bestk[t] = kr; }
            }
        }

        // ---- epilogue B: read back row-major, store 256B-contiguous segments ----
        // instr j: lane covers row = 4j + g, floats fi = col*4..col*4+3
        #pragma unroll
        for (int j = 0; j < 4; ++j) {
            const int row = 4 * j + g;
            const int fi  = col * 4;
            const int sfi = fi ^ (j << 4) ^ (g << 3);
            f32x4 v = *(const f32x4*)&scratch[wave][row][sfi];
            const int kr = kt * 16 + row;
            *(f32x4*)(dist + (size_t)kr * N_PTS + n0 + fi) = v;
        }

        // ---- counted wait: 2 stage + 4 stores outstanding; vmcnt(4) retires
        //      the stage (and older stores), keeps this tile's stores in flight ----
        if (kt + 1 < KTILES) {
            asm volatile("s_waitcnt vmcnt(4)" ::: "memory");
            __builtin_amdgcn_sched_barrier(0);
            __builtin_amdgcn_s_barrier();
            cur ^= 1;
        }
    }

    // ---- cross-lane argmin over the 4 lane groups ----
    #pragma unroll
    for (int t = 0; t < NT; ++t) {
        float d = bestd[t];
        int   k = bestk[t];
        #pragma unroll
        for (int off = 16; off < 64; off <<= 1) {
            float od = __shfl_xor(d, off);
            int   ok = __shfl_xor(k, off);
            if (od < d || (od == d && ok < k)) { d = od; k = ok; }
        }
        if (g == 0) assign_out[n0 + t * 16 + col] = (float)k;
    }
}

extern "C" void kernel_launch(void* const* d_in, const int* in_sizes, int n_in,
                              void* d_out, int out_size, void* d_ws, size_t ws_size,
                              hipStream_t stream) {
    const float* x = (const float*)d_in[0];   // [N, D]
    const float* c = (const float*)d_in[1];   // [K, D]
    float* dist       = (float*)d_out;                 // [K, N]
    float* assign_out = dist + (size_t)KC * N_PTS;     // [N] as float

    // ws: swizzled tiles [32 * 8KB = 256KB] | csq f32[512]
    unsigned char* tiles = (unsigned char*)d_ws;
    float* csq = (float*)(tiles + (size_t)KTILES * TILE_BYTES);

    prep_centroids<<<KC, DIM, 0, stream>>>(c, tiles, csq);
    kmeans_mfma<<<N_PTS / PTS_PER_WG, BLOCK, 0, stream>>>(x, tiles, csq, dist, assign_out);
}

// Round 8
// 86.492 us; speedup vs baseline: 1.1868x; 1.0588x over previous
//
#include <hip/hip_runtime.h>

#define N_PTS 131072
#define DIM   128
#define KC    512
#define NT    4                 // n-tiles (of 16 points) per wave
#define WAVES 4
#define BLOCK (WAVES * 64)
#define PTS_PER_WG (WAVES * NT * 16)   // 256
#define KTILES (KC / 16)               // 32
#define TILE_BYTES 8192                // hi 4KB + lo 4KB per k-tile (swizzled)

typedef _Float16 half8 __attribute__((ext_vector_type(8)));
typedef float    f32x4 __attribute__((ext_vector_type(4)));

// ---------------- prep: centroids fp32 -> swizzled f16 hi/lo tiles + csq --------
// tile kt = [hi 4KB | lo 4KB]; row r (=k&15) at r*256; byte b(dim d)=2d stored
// at b ^ ((r&7)<<4)   (16B-granular XOR swizzle)
__global__ __launch_bounds__(128)
void prep_centroids(const float* __restrict__ c,
                    unsigned char* __restrict__ tiles,
                    float* __restrict__ csq) {
    const int k = blockIdx.x;
    const int d = threadIdx.x;
    float v = c[k * DIM + d];
    _Float16 hi = (_Float16)v;
    _Float16 lo = (_Float16)(v - (float)hi);

    const int kt = k >> 4, row = k & 15;
    const unsigned bsw = (unsigned)(2 * d) ^ (unsigned)((row & 7) << 4);
    unsigned char* tb = tiles + (size_t)kt * TILE_BYTES + row * 256 + bsw;
    *(_Float16*)(tb)        = hi;
    *(_Float16*)(tb + 4096) = lo;

    float s = v * v;
    #pragma unroll
    for (int off = 1; off < 64; off <<= 1) s += __shfl_xor(s, off);
    __shared__ float red[2];
    if ((d & 63) == 0) red[d >> 6] = s;
    __syncthreads();
    if (d == 0) csq[k] = red[0] + red[1];
}

// async global->LDS, 16B per lane (dest = wave-uniform base + lane*16 by HW)
__device__ __forceinline__ void stage16(const void* g, void* l) {
    __builtin_amdgcn_global_load_lds(
        (const __attribute__((address_space(1))) void*)g,
        (__attribute__((address_space(3))) void*)l, 16, 0, 0);
}

// stage one whole 8KB tile for THIS wave (8 x 1KB), private LDS buffer
__device__ __forceinline__ void stage_tile(const unsigned char* src_tile,
                                           unsigned char* dst_tile, int lane) {
    #pragma unroll
    for (int j = 0; j < 8; ++j)
        stage16(src_tile + j * 1024 + lane * 16, dst_tile + j * 1024);
}

// ------------- main: per-wave private A staging, BARRIER-FREE main loop --------
__global__ __launch_bounds__(BLOCK, 2)
void kmeans_mfma(const float* __restrict__ x,
                 const unsigned char* __restrict__ tiles,
                 const float* __restrict__ csq,
                 float* __restrict__ dist,
                 float* __restrict__ assign_out) {
    __shared__ alignas(16) unsigned char abuf[2][WAVES][TILE_BYTES];  // 64 KB
    __shared__ alignas(16) float csq_lds[KC];                          // 2 KB

    const int tid  = threadIdx.x;
    const int wave = tid >> 6;
    const int lane = tid & 63;
    const int col  = lane & 15;       // n within tile / A row within k-tile
    const int g    = lane >> 4;       // lane group -> k-slot block / C row group
    const int n0   = blockIdx.x * PTS_PER_WG + wave * (NT * 16);

    // ---- stage tile 0 into this wave's private buffer (overlaps B-frag loads) --
    stage_tile(tiles, &abuf[0][wave][0], lane);

    // ---- csq -> LDS (shared read-only; one barrier before loop covers it) ----
    csq_lds[tid]       = csq[tid];
    csq_lds[tid + 256] = csq[tid + 256];

    // ---- B-frags: this wave's 64 points, hi/lo f16, resident in VGPRs ----
    half8 bhi[NT][4], blo[NT][4];
    float xsq[NT];
    #pragma unroll
    for (int t = 0; t < NT; ++t) {
        const float* xp = x + (size_t)(n0 + t * 16 + col) * DIM;
        float s = 0.f;
        #pragma unroll
        for (int sb = 0; sb < 4; ++sb) {
            const int dbase = sb * 32 + g * 8;
            float4 v0 = *(const float4*)(xp + dbase);
            float4 v1 = *(const float4*)(xp + dbase + 4);
            float vv[8] = {v0.x, v0.y, v0.z, v0.w, v1.x, v1.y, v1.z, v1.w};
            half8 h, l;
            #pragma unroll
            for (int j = 0; j < 8; ++j) {
                _Float16 hh = (_Float16)vv[j];
                h[j] = hh;
                l[j] = (_Float16)(vv[j] - (float)hh);
                s = fmaf(vv[j], vv[j], s);
            }
            bhi[t][sb] = h;
            blo[t][sb] = l;
        }
        s += __shfl_xor(s, 16);
        s += __shfl_xor(s, 32);
        xsq[t] = s;
    }

    float bestd[NT];
    int   bestk[NT];
    #pragma unroll
    for (int t = 0; t < NT; ++t) { bestd[t] = INFINITY; bestk[t] = 0; }

    asm volatile("s_waitcnt vmcnt(0)" ::: "memory");  // tile-0 stage complete
    __syncthreads();                                  // csq_lds visible (one-time)

    int cur = 0;
    for (int kt = 0; kt < KTILES; ++kt) {
        // ---- issue next tile's private stage FIRST (hides under MFMA+stores) ----
        if (kt + 1 < KTILES) {
            stage_tile(tiles + (size_t)(kt + 1) * TILE_BYTES,
                       &abuf[cur ^ 1][wave][0], lane);
        }
        __builtin_amdgcn_sched_barrier(0);

        // ---- A-frags from private LDS (swizzled read matches prep layout) ----
        const unsigned char* buf = &abuf[cur][wave][0];
        half8 Ah[4], Al[4];
        #pragma unroll
        for (int sb = 0; sb < 4; ++sb) {
            const unsigned b = (unsigned)((sb * 64 + g * 16) ^ ((col & 7) << 4));
            Ah[sb] = *(const half8*)(buf + col * 256 + b);
            Al[sb] = *(const half8*)(buf + 4096 + col * 256 + b);
        }
        f32x4 cs4 = *(const f32x4*)(&csq_lds[kt * 16 + g * 4]);

        // ---- MFMA: 3-pass split-f16, NT independent chains ----
        f32x4 acc[NT];
        #pragma unroll
        for (int t = 0; t < NT; ++t) {
            f32x4 a_ = {0.f, 0.f, 0.f, 0.f};
            #pragma unroll
            for (int sb = 0; sb < 4; ++sb) {
                a_ = __builtin_amdgcn_mfma_f32_16x16x32_f16(Ah[sb], bhi[t][sb], a_, 0, 0, 0);
                a_ = __builtin_amdgcn_mfma_f32_16x16x32_f16(Ah[sb], blo[t][sb], a_, 0, 0, 0);
                a_ = __builtin_amdgcn_mfma_f32_16x16x32_f16(Al[sb], bhi[t][sb], a_, 0, 0, 0);
            }
            acc[t] = a_;
        }

        // ---- epilogue: direct stores (L2 merges 64B segments) + argmin ----
        #pragma unroll
        for (int r = 0; r < 4; ++r) {
            const int kr = kt * 16 + g * 4 + r;
            float* drow = dist + (size_t)kr * N_PTS + n0 + col;
            #pragma unroll
            for (int t = 0; t < NT; ++t) {
                float dv = fmaf(-2.f, acc[t][r], xsq[t] + cs4[r]);
                drow[t * 16] = dv;
                if (dv < bestd[t]) { bestd[t] = dv; bestk[t] = kr; }
            }
        }

        // ---- per-wave counted wait, NO barrier: in-order retire means
        //      vmcnt(16) retires prev-tile stores + next-tile stage,
        //      leaves this tile's 16 stores in flight ----
        if (kt + 1 < KTILES) {
            asm volatile("s_waitcnt vmcnt(16)" ::: "memory");
            __builtin_amdgcn_sched_barrier(0);
            cur ^= 1;
        }
    }

    // ---- cross-lane argmin over the 4 lane groups ----
    #pragma unroll
    for (int t = 0; t < NT; ++t) {
        float d = bestd[t];
        int   k = bestk[t];
        #pragma unroll
        for (int off = 16; off < 64; off <<= 1) {
            float od = __shfl_xor(d, off);
            int   ok = __shfl_xor(k, off);
            if (od < d || (od == d && ok < k)) { d = od; k = ok; }
        }
        if (g == 0) assign_out[n0 + t * 16 + col] = (float)k;
    }
}

extern "C" void kernel_launch(void* const* d_in, const int* in_sizes, int n_in,
                              void* d_out, int out_size, void* d_ws, size_t ws_size,
                              hipStream_t stream) {
    const float* x = (const float*)d_in[0];   // [N, D]
    const float* c = (const float*)d_in[1];   // [K, D]
    float* dist       = (float*)d_out;                 // [K, N]
    float* assign_out = dist + (size_t)KC * N_PTS;     // [N] as float

    // ws: swizzled tiles [32 * 8KB = 256KB] | csq f32[512]
    unsigned char* tiles = (unsigned char*)d_ws;
    float* csq = (float*)(tiles + (size_t)KTILES * TILE_BYTES);

    prep_centroids<<<KC, DIM, 0, stream>>>(c, tiles, csq);
    kmeans_mfma<<<N_PTS / PTS_PER_WG, BLOCK, 0, stream>>>(x, tiles, csq, dist, assign_out);
}